// Round 4
// baseline (182.881 us; speedup 1.0000x reference)
//
#include <hip/hip_runtime.h>
#include <float.h>
#include <stdint.h>

#define CC 256
#define HH 200
#define WW 320
#define HW (HH * WW)
#define MM 14
#define CG 4             // channel-group blocks per (roi, bin-row)
#define CPB (CC / CG)    // 64 channels per block
#define KPW (CPB / 4)    // 16 channels per wave
#define SP4 38           // float4 slots per (ch,row) LDS run (span4 <= 37)
#define SPF (SP4 * 4)    // 152 floats; row stride 152 % 32 = 24 -> i-pair bank split

__global__ void roi_init(float* __restrict__ binmax) {
    int t = blockIdx.x * blockDim.x + threadIdx.x;
    if (t < MM * MM) binmax[t] = -FLT_MAX;
}

__device__ inline void atomicMaxF(float* addr, float val) {
    // Ordered-int trick: valid for finite floats.
    if (val >= 0.0f) {
        atomicMax((int*)addr, __float_as_int(val));
    } else {
        atomicMin((unsigned int*)addr, __float_as_uint(val));
    }
}

__device__ __forceinline__ void gload_lds16(const float* g, float* l) {
    // 16B-per-lane DMA: LDS dest = wave-uniform base + lane*16.
    __builtin_amdgcn_global_load_lds(
        (const __attribute__((address_space(1))) unsigned int*)g,
        (__attribute__((address_space(3))) unsigned int*)l,
        16, 0, 0);
}

// Barrier-free roi_reduce: each wave owns 16 channels and a private LDS
// slice (dbuf x 4 rows x SPF). No s_barrier in the main loop -- ordering is
// purely s_waitcnt (vmcnt counted, lgkmcnt drained before buffer overwrite).
__global__ __launch_bounds__(256, 8) void roi_reduce(
    const float* __restrict__ feature,
    const float* __restrict__ rois,
    float* __restrict__ binmax)
{
    const int bid = blockIdx.x;
    const int cg  = bid & (CG - 1);
    const int rm  = bid >> 2;          // CG == 4
    const int m   = rm % MM;
    const int r   = rm / MM;
    const int tid = threadIdx.x;
    const int w    = tid >> 6;         // wave id 0..3
    const int lane = tid & 63;
    const int cbase = cg * CPB + w * KPW;   // this wave's first channel

    const float ry1 = rois[r * 4 + 0];
    const float rx1 = rois[r * 4 + 1];
    const float ry2 = rois[r * 4 + 2];
    const float rx2 = rois[r * 4 + 3];
    const float sh = (ry2 - ry1) * (1.0f / 14.0f);
    const float sw = (rx2 - rx1) * (1.0f / 14.0f);
    const float f13 = 1.0f / 3.0f, f23 = 2.0f / 3.0f;

    // Two y sample coords for this bin-row m (reference clamp semantics).
    const float yA = ry1 + sh * (float)m + sh * f13;
    const float yB = ry1 + sh * (float)m + sh * f23;
    const int y1A = min(max((int)floorf(yA), 0), HH - 1);
    const int y2A = min(max((int)floorf(yA) + 1, 0), HH - 1);
    const int y1B = min(max((int)floorf(yB), 0), HH - 1);
    const int y2B = min(max((int)floorf(yB) + 1, 0), HH - 1);
    const float wyloA = yA - (float)y1A, wyhiA = (float)y2A - yA;
    const float wyloB = yB - (float)y1B, wyhiB = (float)y2B - yB;

    // Column window covering all 28 x sample points' corners, 4-aligned.
    const float xmin = rx1 + sw * f13;
    const float xmax = rx1 + sw * 13.0f + sw * f23;
    int xlo = min(max((int)floorf(xmin), 0), WW - 1);
    int xhi = min(max((int)floorf(xmax) + 1, 0), WW - 1);
    const int xlo4 = xlo & ~3;
    int span = xhi - xlo4 + 1;
    if (span > 4 * SP4 - 4) span = 4 * SP4 - 4;   // cannot trigger with given bounds
    const int span4 = (span + 3) >> 2;            // <= 37 (< SP4)

    // Compute mapping: lane = n*4 + j*2 + i ; lanes 56..63 ride along.
    const int n = lane >> 2;
    const int j = (lane >> 1) & 1;
    const int i = lane & 1;
    const bool active = (lane < 56);

    float wxlo = 0.f, wxhi = 0.f, wylo = 0.f, wyhi = 0.f;
    int c0 = 0, c1 = 0, ra = 0, rb = 1;
    if (active) {
        float x = rx1 + sw * (float)n + sw * (j ? f23 : f13);
        int x1c = min(max((int)floorf(x), 0), WW - 1);
        int x2c = min(max((int)floorf(x) + 1, 0), WW - 1);
        wxlo = x - (float)x1c;
        wxhi = (float)x2c - x;
        c0 = min(max(x1c - xlo4, 0), span - 1);
        c1 = min(max(x2c - xlo4, 0), span - 1);
        if (i == 0) { ra = 0; rb = 1; wylo = wyloA; wyhi = wyhiA; }
        else        { ra = 2; rb = 3; wylo = wyloB; wyhi = wyhiB; }
    }

    // Per-wave private double-buffered tile: [wave][buf][row][SPF] = 19456 B.
    __shared__ float tileF[4][2][4][SPF];
    float* ldsW = &tileF[w][0][0][0];

    const float* gBase = feature + (size_t)cbase * HW + xlo4 + (lane << 2);
    const int o0 = y1A * WW, o1 = y2A * WW, o2 = y1B * WW, o3 = y2B * WW;
    const bool ld = lane < span4;   // span4 >= 1

    // Buf-fixed LDS read pointers (addresses constant across the loop).
    const float* p0a = ldsW + 0 * 4 * SPF + ra * SPF;
    const float* p0b = ldsW + 0 * 4 * SPF + rb * SPF;
    const float* p1a = ldsW + 1 * 4 * SPF + ra * SPF;
    const float* p1b = ldsW + 1 * 4 * SPF + rb * SPF;

    #define STAGE(kk, bb) do { if (ld) {                                  \
        const float* g_ = gBase + (size_t)(kk) * HW;                      \
        gload_lds16(g_ + o0, ldsW + (bb) * 4 * SPF + 0 * SPF);            \
        gload_lds16(g_ + o1, ldsW + (bb) * 4 * SPF + 1 * SPF);            \
        gload_lds16(g_ + o2, ldsW + (bb) * 4 * SPF + 2 * SPF);            \
        gload_lds16(g_ + o3, ldsW + (bb) * 4 * SPF + 3 * SPF); } } while (0)

    STAGE(0, 0);
    float lmax = -FLT_MAX;

    for (int k = 0; k < KPW; k += 2) {
        // --- even channel k: buf 0 ---
        // Drain this wave's LDS reads (from k-1 in buf1) before overwriting buf1.
        asm volatile("s_waitcnt lgkmcnt(0)" ::: "memory");
        if (k + 1 < KPW) {
            STAGE(k + 1, 1);
            asm volatile("s_waitcnt vmcnt(4)" ::: "memory");  // ch k landed
        } else {
            asm volatile("s_waitcnt vmcnt(0)" ::: "memory");
        }
        {
            float v11 = p0a[c0], v12 = p0a[c1];
            float v21 = p0b[c0], v22 = p0b[c1];
            float p  = v11 * wxhi + v12 * wxlo;
            float q2 = v21 * wxhi + v22 * wxlo;
            lmax = fmaxf(lmax, p * wyhi + q2 * wylo);
        }
        // --- odd channel k+1: buf 1 ---
        asm volatile("s_waitcnt lgkmcnt(0)" ::: "memory");  // buf0 reads done
        if (k + 2 < KPW) {
            STAGE(k + 2, 0);
            asm volatile("s_waitcnt vmcnt(4)" ::: "memory");  // ch k+1 landed
        } else {
            asm volatile("s_waitcnt vmcnt(0)" ::: "memory");
        }
        {
            float v11 = p1a[c0], v12 = p1a[c1];
            float v21 = p1b[c0], v22 = p1b[c1];
            float p  = v11 * wxhi + v12 * wxlo;
            float q2 = v21 * wxhi + v22 * wxlo;
            lmax = fmaxf(lmax, p * wyhi + q2 * wylo);
        }
    }
    #undef STAGE

    // Partials: reuse own (dead) tile slice as pmax storage — wave-private,
    // so no barrier needed before the write; one barrier before reduction.
    if (active) ldsW[lane] = lmax;
    __syncthreads();
    if (tid < MM) {  // one thread per bin n
        float v = -FLT_MAX;
        #pragma unroll
        for (int w4 = 0; w4 < 4; ++w4)
            #pragma unroll
            for (int q4 = 0; q4 < 4; ++q4)
                v = fmaxf(v, tileF[w4][0][0][tid * 4 + q4]);
        atomicMaxF(&binmax[m * MM + tid], v);
    }
}

__global__ __launch_bounds__(256) void roi_bcast(
    const float* __restrict__ binmax, float4* __restrict__ out, int total4)
{
    __shared__ float4 b4[49];  // 196 floats = 49 float4, aligned with bin period
    int t = threadIdx.x;
    if (t < 49) b4[t] = ((const float4*)binmax)[t];
    __syncthreads();
    const int stride = gridDim.x * 256;
    for (int idx = blockIdx.x * 256 + t; idx < total4; idx += stride)
        out[idx] = b4[idx % 49];
}

extern "C" void kernel_launch(void* const* d_in, const int* in_sizes, int n_in,
                              void* d_out, int out_size, void* d_ws, size_t ws_size,
                              hipStream_t stream) {
    const float* feature = (const float*)d_in[0];
    const float* rois    = (const float*)d_in[1];
    float* binmax = (float*)d_ws;
    float* out    = (float*)d_out;

    const int R = in_sizes[1] / 4;

    roi_init<<<1, 256, 0, stream>>>(binmax);
    roi_reduce<<<R * MM * CG, 256, 0, stream>>>(feature, rois, binmax);

    const int total4 = out_size / 4;
    int nb = (total4 + 255) / 256;
    if (nb > 2048) nb = 2048;
    roi_bcast<<<nb, 256, 0, stream>>>(binmax, (float4*)out, total4);
}

// Round 5
// 162.167 us; speedup vs baseline: 1.1277x; 1.1277x over previous
//
#include <hip/hip_runtime.h>
#include <float.h>
#include <stdint.h>

#define CC 256
#define HH 200
#define WW 320
#define HW (HH * WW)
#define MM 14
#define NCH 8            // channels staged per barrier round (v0's fat rounds)
#define CG 4             // channel-group blocks per (roi, bin-row)
#define CPB (CC / CG)    // 64 channels per block
#define SP4 38           // float4 slots per (ch,row) LDS run (span4 <= 38)
#define SPF (SP4 * 4)    // 152 floats; row stride 152 % 32 = 24 -> i-pair bank split

__global__ void roi_init(float* __restrict__ binmax) {
    int t = blockIdx.x * blockDim.x + threadIdx.x;
    if (t < MM * MM) binmax[t] = -FLT_MAX;
}

__device__ inline void atomicMaxF(float* addr, float val) {
    // Ordered-int trick: valid for finite floats.
    if (val >= 0.0f) {
        atomicMax((int*)addr, __float_as_int(val));
    } else {
        atomicMin((unsigned int*)addr, __float_as_uint(val));
    }
}

__device__ __forceinline__ void gload_lds16(const float* g, float* l) {
    // 16B-per-lane DMA: LDS dest = wave-uniform base + lane*16.
    __builtin_amdgcn_global_load_lds(
        (const __attribute__((address_space(1))) unsigned int*)g,
        (__attribute__((address_space(3))) unsigned int*)l,
        16, 0, 0);
}

// v0 structure (fat 8-channel rounds, 2 __syncthreads per round, 8 blocks/CU,
// 4 loader waves each owning one feature row) with the staging path swapped
// from {scalar global load -> VGPR -> ds_write_b32} to global_load_lds DMA.
__global__ __launch_bounds__(256, 8) void roi_reduce(
    const float* __restrict__ feature,
    const float* __restrict__ rois,
    float* __restrict__ binmax)
{
    const int bid = blockIdx.x;
    const int cg  = bid & (CG - 1);
    const int rm  = bid >> 2;          // CG == 4
    const int m   = rm % MM;
    const int r   = rm / MM;
    const int tid = threadIdx.x;
    const int cbase = cg * CPB;

    const float ry1 = rois[r * 4 + 0];
    const float rx1 = rois[r * 4 + 1];
    const float ry2 = rois[r * 4 + 2];
    const float rx2 = rois[r * 4 + 3];
    const float sh = (ry2 - ry1) * (1.0f / 14.0f);
    const float sw = (rx2 - rx1) * (1.0f / 14.0f);
    const float f13 = 1.0f / 3.0f, f23 = 2.0f / 3.0f;

    // Two y sample coords for this bin-row m (reference clamp semantics).
    const float yA = ry1 + sh * (float)m + sh * f13;
    const float yB = ry1 + sh * (float)m + sh * f23;
    const int y1A = min(max((int)floorf(yA), 0), HH - 1);
    const int y2A = min(max((int)floorf(yA) + 1, 0), HH - 1);
    const int y1B = min(max((int)floorf(yB), 0), HH - 1);
    const int y2B = min(max((int)floorf(yB) + 1, 0), HH - 1);
    const float wyloA = yA - (float)y1A, wyhiA = (float)y2A - yA;
    const float wyloB = yB - (float)y1B, wyhiB = (float)y2B - yB;

    // Column window covering all 28 x sample points' corners, 4-aligned so
    // the 16B DMA loads are aligned.
    const float xmin = rx1 + sw * f13;
    const float xmax = rx1 + sw * 13.0f + sw * f23;
    int xlo = min(max((int)floorf(xmin), 0), WW - 1);
    int xhi = min(max((int)floorf(xmax) + 1, 0), WW - 1);
    const int xlo4 = xlo & ~3;
    int span = xhi - xlo4 + 1;
    if (span > 4 * SP4 - 4) span = 4 * SP4 - 4;   // cannot trigger with given bounds
    const int span4 = (span + 3) >> 2;            // <= 38

    // Compute-thread mapping: tid = s + 56*cs ; s = n*4 + j*2 + i
    const int s  = tid % 56;
    const int cs = tid / 56;        // channel sub-index 0..3 (tid>=224 -> loader-only)
    const int n  = s >> 2;
    const int j  = (s >> 1) & 1;
    const int i  = s & 1;
    const bool active = (tid < 224);

    float wxlo = 0.f, wxhi = 0.f, wylo = 0.f, wyhi = 0.f;
    int c0 = 0, c1 = 0, ra = 0, rb = 1;
    if (active) {
        float x = rx1 + sw * (float)n + sw * (j ? f23 : f13);
        int x1c = min(max((int)floorf(x), 0), WW - 1);
        int x2c = min(max((int)floorf(x) + 1, 0), WW - 1);
        wxlo = x - (float)x1c;
        wxhi = (float)x2c - x;
        c0 = min(max(x1c - xlo4, 0), span - 1);
        c1 = min(max(x2c - xlo4, 0), span - 1);
        if (i == 0) { ra = 0; rb = 1; wylo = wyloA; wyhi = wyhiA; }
        else        { ra = 2; rb = 3; wylo = wyloB; wyhi = wyhiB; }
    }

    // Single-buffer DMA tile: 8*4*152*4 = 19456 B (+ pmax 896 B) -> 8 blocks/CU.
    __shared__ float tileF[NCH][4][SPF];
    __shared__ float pmax[224];

    // Loader mapping: wave rg owns one feature row; lane = float4 column.
    const int rg   = tid >> 6;
    const int lane = tid & 63;
    const int myrow = (rg == 0) ? y1A : (rg == 1) ? y2A : (rg == 2) ? y1B : y2B;
    const float* gRow = feature + cbase * HW + myrow * WW + xlo4 + (lane << 2);
    const bool ld = lane < span4;

    float lmax = -FLT_MAX;

    for (int cc = 0; cc < CPB; cc += NCH) {
        __syncthreads();   // prev round's reads done -> tile overwritable
        if (ld) {
            const float* g = gRow + (size_t)cc * HW;
            #pragma unroll
            for (int ch = 0; ch < NCH; ++ch) {
                gload_lds16(g, &tileF[ch][rg][0]);
                g += HW;
            }
        }
        __syncthreads();   // implicit vmcnt(0): all 4 waves' DMA landed
        if (active) {
            #pragma unroll
            for (int q = 0; q < 2; ++q) {
                const int ch = cs * 2 + q;
                float v11 = tileF[ch][ra][c0];
                float v12 = tileF[ch][ra][c1];
                float v21 = tileF[ch][rb][c0];
                float v22 = tileF[ch][rb][c1];
                float p  = v11 * wxhi + v12 * wxlo;
                float q2 = v21 * wxhi + v22 * wxlo;
                lmax = fmaxf(lmax, p * wyhi + q2 * wylo);
            }
        }
    }

    if (active) pmax[tid] = lmax;
    __syncthreads();
    if (tid < MM) {  // one thread per bin n
        float v = -FLT_MAX;
        #pragma unroll
        for (int c4 = 0; c4 < 4; ++c4)
            #pragma unroll
            for (int q4 = 0; q4 < 4; ++q4)
                v = fmaxf(v, pmax[c4 * 56 + tid * 4 + q4]);
        atomicMaxF(&binmax[m * MM + tid], v);
    }
}

__global__ __launch_bounds__(256) void roi_bcast(
    const float* __restrict__ binmax, float4* __restrict__ out, int total4)
{
    __shared__ float4 b4[49];  // 196 floats = 49 float4, aligned with bin period
    int t = threadIdx.x;
    if (t < 49) b4[t] = ((const float4*)binmax)[t];
    __syncthreads();
    const int stride = gridDim.x * 256;
    for (int idx = blockIdx.x * 256 + t; idx < total4; idx += stride)
        out[idx] = b4[idx % 49];
}

extern "C" void kernel_launch(void* const* d_in, const int* in_sizes, int n_in,
                              void* d_out, int out_size, void* d_ws, size_t ws_size,
                              hipStream_t stream) {
    const float* feature = (const float*)d_in[0];
    const float* rois    = (const float*)d_in[1];
    float* binmax = (float*)d_ws;
    float* out    = (float*)d_out;

    const int R = in_sizes[1] / 4;

    roi_init<<<1, 256, 0, stream>>>(binmax);
    roi_reduce<<<R * MM * CG, 256, 0, stream>>>(feature, rois, binmax);

    const int total4 = out_size / 4;
    int nb = (total4 + 255) / 256;
    if (nb > 2048) nb = 2048;
    roi_bcast<<<nb, 256, 0, stream>>>(binmax, (float4*)out, total4);
}

// Round 7
// 146.933 us; speedup vs baseline: 1.2447x; 1.1037x over previous
//
#include <hip/hip_runtime.h>
#include <float.h>

#define CC 256
#define HH 200
#define WW 320
#define HW (HH * WW)
#define MM 14
#define SPAN_MAX 144
#define SPAN_PAD 145
#define NCH 8            // channels staged per barrier round
#define CG 4             // channel-group blocks per (roi, bin-row)
#define CPB (CC / CG)    // 64 channels per block
#define NR (CPB / NCH)   // 8 rounds

__global__ void roi_init(float* __restrict__ binmax) {
    int t = blockIdx.x * blockDim.x + threadIdx.x;
    if (t < MM * MM) binmax[t] = -FLT_MAX;
}

__device__ inline void atomicMaxF(float* addr, float val) {
    // Ordered-int trick: valid for finite floats.
    if (val >= 0.0f) {
        atomicMax((int*)addr, __float_as_int(val));
    } else {
        atomicMin((unsigned int*)addr, __float_as_uint(val));
    }
}

// v0 structure (fat 8-channel rounds, loader waves own one feature row each,
// 19.5 KB LDS -> 8 blocks/CU, lockstep rounds) + T14 async-STAGE split:
// round k+1's global loads are issued into registers right after round k's
// LDS writes, and only waited on (counted vmcnt, raw s_barrier -- no
// structural vmcnt(0)-before-barrier drain) at the top of round k+1. The
// global latency hides under round k's compute across 8 resident blocks.
__global__ __launch_bounds__(256, 8) void roi_reduce(
    const float* __restrict__ feature,
    const float* __restrict__ rois,
    float* __restrict__ binmax)
{
    const int bid = blockIdx.x;
    const int cg  = bid & (CG - 1);
    const int rm  = bid >> 2;          // CG == 4
    const int m   = rm % MM;
    const int r   = rm / MM;
    const int tid = threadIdx.x;
    const int cbase = cg * CPB;

    const float ry1 = rois[r * 4 + 0];
    const float rx1 = rois[r * 4 + 1];
    const float ry2 = rois[r * 4 + 2];
    const float rx2 = rois[r * 4 + 3];
    const float sh = (ry2 - ry1) * (1.0f / 14.0f);
    const float sw = (rx2 - rx1) * (1.0f / 14.0f);
    const float f13 = 1.0f / 3.0f, f23 = 2.0f / 3.0f;

    // Two y sample coords for this bin-row m (reference clamp semantics).
    const float yA = ry1 + sh * (float)m + sh * f13;
    const float yB = ry1 + sh * (float)m + sh * f23;
    const int y1A = min(max((int)floorf(yA), 0), HH - 1);
    const int y2A = min(max((int)floorf(yA) + 1, 0), HH - 1);
    const int y1B = min(max((int)floorf(yB), 0), HH - 1);
    const int y2B = min(max((int)floorf(yB) + 1, 0), HH - 1);
    const float wyloA = yA - (float)y1A, wyhiA = (float)y2A - yA;
    const float wyloB = yB - (float)y1B, wyhiB = (float)y2B - yB;

    // Column window covering all 28 x sample points' corners.
    const float xmin = rx1 + sw * f13;
    const float xmax = rx1 + sw * 13.0f + sw * f23;
    int xlo = min(max((int)floorf(xmin), 0), WW - 1);
    int xhi = min(max((int)floorf(xmax) + 1, 0), WW - 1);
    int span = xhi - xlo + 1;
    if (span > SPAN_MAX) span = SPAN_MAX;  // cannot trigger with given input bounds

    // Compute-thread mapping: tid = s + 56*cs ; s = n*4 + j*2 + i
    const int s  = tid % 56;
    const int cs = tid / 56;        // channel sub-index 0..3 (tid>=224 -> loader-only)
    const int n  = s >> 2;
    const int j  = (s >> 1) & 1;
    const int i  = s & 1;
    const bool active = (tid < 224);

    float wxlo = 0.f, wxhi = 0.f, wylo = 0.f, wyhi = 0.f;
    int c0 = 0, c1 = 0, ra = 0, rb = 1;
    if (active) {
        float x = rx1 + sw * (float)n + sw * (j ? f23 : f13);
        int x1c = min(max((int)floorf(x), 0), WW - 1);
        int x2c = min(max((int)floorf(x) + 1, 0), WW - 1);
        wxlo = x - (float)x1c;
        wxhi = (float)x2c - x;
        c0 = min(max(x1c - xlo, 0), span - 1);
        c1 = min(max(x2c - xlo, 0), span - 1);
        if (i == 0) { ra = 0; rb = 1; wylo = wyloA; wyhi = wyhiA; }
        else        { ra = 2; rb = 3; wylo = wyloB; wyhi = wyhiB; }
    }

    __shared__ float tile[NCH][4][SPAN_PAD];  // 18.56 KB
    __shared__ float pmax[224];

    // Loader mapping: 4 waves, one feature row each; static col slots so the
    // prefetched values live in registers (no runtime-indexed arrays).
    const int rg   = tid >> 6;
    const int lane = tid & 63;
    const int myrow = (rg == 0) ? y1A : (rg == 1) ? y2A : (rg == 2) ? y1B : y2B;
    const float* src0 = feature + cbase * HW + myrow * WW + xlo;

    const int colA = lane;
    const int colB = lane + 64;
    const int colC = lane + 128;
    const bool mA = colA < span;
    const bool mB = colB < span;
    const bool mC = colC < span;   // span <= 144 -> colC covers the tail

    float tA[NCH], tB[NCH], tC[NCH];

    #define ISSUE(cc) do {                                                   \
        const float* s_ = src0 + (cc) * HW;                                  \
        if (mA) { _Pragma("unroll")                                          \
            for (int ch = 0; ch < NCH; ++ch) tA[ch] = s_[ch * HW + colA]; }  \
        if (mB) { _Pragma("unroll")                                          \
            for (int ch = 0; ch < NCH; ++ch) tB[ch] = s_[ch * HW + colB]; }  \
        if (mC) { _Pragma("unroll")                                          \
            for (int ch = 0; ch < NCH; ++ch) tC[ch] = s_[ch * HW + colC]; }  \
    } while (0)

    ISSUE(0);
    float lmax = -FLT_MAX;

    for (int k = 0; k < NR; ++k) {
        // [A] this round's prefetched regs have landed (issued last round;
        // latency hid under last round's compute + 7 other resident blocks).
        asm volatile("s_waitcnt vmcnt(0)" ::: "memory");
        // [B] all waves' previous compute done -> tile overwritable.
        __builtin_amdgcn_s_barrier();
        asm volatile("" ::: "memory");

        // [C] registers -> LDS (same layout/pattern as v0).
        if (mA) {
            #pragma unroll
            for (int ch = 0; ch < NCH; ++ch) tile[ch][rg][colA] = tA[ch];
        }
        if (mB) {
            #pragma unroll
            for (int ch = 0; ch < NCH; ++ch) tile[ch][rg][colB] = tB[ch];
        }
        if (mC) {
            #pragma unroll
            for (int ch = 0; ch < NCH; ++ch) tile[ch][rg][colC] = tC[ch];
        }

        // [D] issue next round's loads NOW -- they stay in flight across the
        // barrier and the compute phase (counted wait, not drained here).
        if (k + 1 < NR) ISSUE((k + 1) * NCH);

        // [E] my LDS writes complete; [F] everyone's writes visible.
        asm volatile("s_waitcnt lgkmcnt(0)" ::: "memory");
        __builtin_amdgcn_s_barrier();
        asm volatile("" ::: "memory");

        // [G] compute on the tile (identical to v0).
        if (active) {
            #pragma unroll
            for (int q = 0; q < 2; ++q) {
                const int ch = cs * 2 + q;
                float v11 = tile[ch][ra][c0];
                float v12 = tile[ch][ra][c1];
                float v21 = tile[ch][rb][c0];
                float v22 = tile[ch][rb][c1];
                float p  = v11 * wxhi + v12 * wxlo;
                float q2 = v21 * wxhi + v22 * wxlo;
                lmax = fmaxf(lmax, p * wyhi + q2 * wylo);
            }
        }
    }
    #undef ISSUE

    if (active) pmax[tid] = lmax;
    __syncthreads();
    if (tid < MM) {  // one thread per bin n
        float v = -FLT_MAX;
        #pragma unroll
        for (int c4 = 0; c4 < 4; ++c4)
            #pragma unroll
            for (int q4 = 0; q4 < 4; ++q4)
                v = fmaxf(v, pmax[c4 * 56 + tid * 4 + q4]);
        atomicMaxF(&binmax[m * MM + tid], v);
    }
}

__global__ __launch_bounds__(256) void roi_bcast(
    const float* __restrict__ binmax, float4* __restrict__ out, int total4)
{
    __shared__ float4 b4[49];  // 196 floats = 49 float4, aligned with bin period
    int t = threadIdx.x;
    if (t < 49) b4[t] = ((const float4*)binmax)[t];
    __syncthreads();
    const int stride = gridDim.x * 256;
    for (int idx = blockIdx.x * 256 + t; idx < total4; idx += stride)
        out[idx] = b4[idx % 49];
}

extern "C" void kernel_launch(void* const* d_in, const int* in_sizes, int n_in,
                              void* d_out, int out_size, void* d_ws, size_t ws_size,
                              hipStream_t stream) {
    const float* feature = (const float*)d_in[0];
    const float* rois    = (const float*)d_in[1];
    float* binmax = (float*)d_ws;
    float* out    = (float*)d_out;

    const int R = in_sizes[1] / 4;

    roi_init<<<1, 256, 0, stream>>>(binmax);
    roi_reduce<<<R * MM * CG, 256, 0, stream>>>(feature, rois, binmax);

    const int total4 = out_size / 4;
    int nb = (total4 + 255) / 256;
    if (nb > 2048) nb = 2048;
    roi_bcast<<<nb, 256, 0, stream>>>(binmax, (float4*)out, total4);
}